// Round 5
// baseline (1288.304 us; speedup 1.0000x reference)
//
#include <hip/hip_runtime.h>
#include <math.h>

// Sliced Wasserstein-2: for each (b,c,p): W2^2 = mean_i (sort(X@theta_p) - sort(Y@theta_p))^2
// loss = mean_{b,c} sqrt(mean_p W2^2)
//
// R21 = R19 ladder (flip-space CE of R20 REVERTED: measured +30% VALU, fold
// didn't land) + two structural fixes:
//  (a) equalized chunks ch=ceil(1600/nch): within-dispatch backfill makes
//      halfsort time ~ (blocks/1024 slots)*T_block; equal chunks avoid the
//      64-slice remainder paying a full round latency. 7 -> 6.25 round-times.
//  (b) swd_mergehalf: the 32K final merge = global b14 CE (rank q vs q+16K
//      across [asc|desc]) + two INDEPENDENT 16K bitonic merges. One 512-thr
//      block per (slice,half): b14 X -> merge16k X (in regs), b14 Y ->
//      merge16k Y, diff in-register, partial sum to w2h[slice*2+h].
//      32KB LDS, <=128 VGPR -> 2 blocks/CU; staged halves are L3-resident.
//      Kills the sorted-X HBM round-trip and the 1-block/CU barrier stalls.
// Sort network identical to R19 -> same permutation; only the w2 reduction
// tree changes (two half-partials summed in swd_final).

namespace {
constexpr int Bb = 8, Cc = 4, Nn = 32768, Pp = 50;
constexpr int T1024 = 1024, T512 = 512;
constexpr int VPT = 32;                    // values per thread
constexpr int SLICES = Bb * Cc * Pp;       // 1600
constexpr size_t W2_BYTES = 16384;         // w2h[3200] partials
constexpr int LDS_FLOATS_FULL = Nn / 2;    // 16384 floats = 64 KB (legacy 1024-thr)
constexpr int LDS_FLOATS_HALF = Nn / 4;    // 8192 floats  = 32 KB (512-thr kernels)
}

__device__ __forceinline__ void ce(float& a, float& b, bool up) {
  float lo = fminf(a, b);
  float hi = fmaxf(a, b);
  a = up ? lo : hi;
  b = up ? hi : lo;
}

// 2-VALU compare-select CE: keepMin ? min(v,o) : max(v,o); ties resolve
// consistently on both partners (multiset preserved).
__device__ __forceinline__ float sel_ce(float v, float o, bool keepMin) {
  return ((o < v) != keepMin) ? v : o;
}

// DPP lane move with compile-time control word.
// 0xB1 = quad_perm(1,0,3,2) = xor1; 0x4E = quad_perm(2,3,0,1) = xor2;
// 0x128 = row_ror:8 = xor8 on each 16-lane row.
template<int CTRL>
__device__ __forceinline__ float dpp_move(float x) {
  int i = __builtin_amdgcn_update_dpp(0, __float_as_int(x), CTRL, 0xF, 0xF, true);
  return __int_as_float(i);
}

// cross-lane CE stage with xor-mask M (M=1,2,8 via DPP; M=4,16,32 via bpermute)
template<int M>
__device__ __forceinline__ void stage_xlane(float v[VPT], int tid, bool up) {
  const bool keepMin = (up == ((tid & M) == 0));
  if constexpr (M == 1 || M == 2 || M == 8) {
    constexpr int ctrl = (M == 1) ? 0xB1 : (M == 2) ? 0x4E : 0x128;
#pragma unroll
    for (int r = 0; r < VPT; r++) {
      float o = dpp_move<ctrl>(v[r]);
      v[r] = sel_ce(v[r], o, keepMin);
    }
  } else {
    const int addr = (((tid & 63) ^ M) << 2);
#pragma unroll
    for (int r = 0; r < VPT; r++) {
      float o = __int_as_float(
          __builtin_amdgcn_ds_bpermute(addr, __float_as_int(v[r])));
      v[r] = sel_ce(v[r], o, keepMin);
    }
  }
}

// 5-stage in-register network on the reg-index bits (j=16..1), direction
// uniform per thread via sign-flip trick.
__device__ __forceinline__ void tail_inreg(float v[VPT], bool up) {
  const unsigned flip = up ? 0u : 0x80000000u;
#pragma unroll
  for (int r = 0; r < VPT; r++)
    v[r] = __int_as_float(__float_as_int(v[r]) ^ flip);
#pragma unroll
  for (int j = 16; j > 0; j >>= 1) {
#pragma unroll
    for (int r = 0; r < VPT; r++) {
      if (!(r & j)) {
        float a = v[r], b = v[r | j];
        v[r] = fminf(a, b);
        v[r | j] = fmaxf(a, b);
      }
    }
  }
#pragma unroll
  for (int r = 0; r < VPT; r++)
    v[r] = __int_as_float(__float_as_int(v[r]) ^ flip);
}

// wave-local cross stages (m = MTOP..1) + tail, explicit direction
template<int MTOP>
__device__ __forceinline__ void wave_ladder_tail_up(float v[VPT], int tid, bool up) {
  if constexpr (MTOP >= 32) stage_xlane<32>(v, tid, up);
  if constexpr (MTOP >= 16) stage_xlane<16>(v, tid, up);
  if constexpr (MTOP >= 8)  stage_xlane<8>(v, tid, up);
  if constexpr (MTOP >= 4)  stage_xlane<4>(v, tid, up);
  if constexpr (MTOP >= 2)  stage_xlane<2>(v, tid, up);
  if constexpr (MTOP >= 1)  stage_xlane<1>(v, tid, up);
  tail_inreg(v, up);
}

// direction from bit A of global rank (= tid bit A-5)
template<int A, int MTOP>
__device__ __forceinline__ void wave_stages_and_tail(float v[VPT], int tid) {
  wave_ladder_tail_up<MTOP>(v, tid, ((tid & (1 << (A - 5))) == 0));
}

// Wave-crossing exchange stage (xor-mask m>=64 on tid), element-wise,
// SPLIT through a half-size buffer in two 16-reg rounds. Column layout
// s[r*NT+tid]: conflict-free. Safe split: round-2 writes happen after the
// barrier that ends round-1 reads; v[] is preserved across reads.
template<int NT>
__device__ __forceinline__ void stage_exch(float v[VPT], float* s, int tid,
                                           int m, bool up) {
  const bool keepMin = (up == ((tid & m) == 0));
  const int pt = tid ^ m;
#pragma unroll
  for (int h = 0; h < 2; h++) {
    __syncthreads();                  // prior users of s must finish
#pragma unroll
    for (int r = 0; r < VPT / 2; r++)
      s[r * NT + tid] = v[h * (VPT / 2) + r];
    __syncthreads();
#pragma unroll
    for (int r = 0; r < VPT / 2; r++) {
      float o = s[r * NT + pt];
      v[h * (VPT / 2) + r] = sel_ce(v[h * (VPT / 2) + r], o, keepMin);
    }
  }
}

// in-register merges a=1..4 (k=2..16), compile-time directions
__device__ __forceinline__ void low_merges_inreg(float v[VPT]) {
#pragma unroll
  for (int k = 2; k <= 16; k <<= 1) {
#pragma unroll
    for (int j = k >> 1; j > 0; j >>= 1) {
#pragma unroll
      for (int r = 0; r < VPT; r++)
        if (!(r & j)) ce(v[r], v[r | j], (r & k) == 0);
    }
  }
}

// ---- 16K bitonic sort, 512 threads, final direction uh (true=asc) ----
__device__ __forceinline__ void sort_16k(float v[VPT], float* s, int tid, bool uh) {
  low_merges_inreg(v);
  tail_inreg(v, (tid & 1) == 0);          // a=5
  wave_stages_and_tail<6, 1>(v, tid);
  wave_stages_and_tail<7, 2>(v, tid);
  wave_stages_and_tail<8, 4>(v, tid);
  wave_stages_and_tail<9, 8>(v, tid);
  wave_stages_and_tail<10, 16>(v, tid);
  wave_stages_and_tail<11, 32>(v, tid);
  // a=12: one wave-crossing stage (m=64), dir = tid bit 7
  stage_exch<T512>(v, s, tid, 64, (tid & 128) == 0);
  wave_stages_and_tail<12, 32>(v, tid);
  // a=13: m=128,64, dir = tid bit 8
  {
    const bool u = (tid & 256) == 0;
    stage_exch<T512>(v, s, tid, 128, u);
    stage_exch<T512>(v, s, tid, 64, u);
  }
  wave_stages_and_tail<13, 32>(v, tid);
  // a=14 (final): dir = uh uniformly
  stage_exch<T512>(v, s, tid, 256, uh);
  stage_exch<T512>(v, s, tid, 128, uh);
  stage_exch<T512>(v, s, tid, 64, uh);
  wave_ladder_tail_up<32>(v, tid, uh);
}

// ---- 16K bitonic MERGE (input bitonic, output ascending), 512 threads ----
// rank q = tid*32 + r (14 bits): b13->m=256, b12->m=128, b11->m=64,
// b10..b5 wave ladder, b4..b0 reg tail. All directions ascending.
__device__ __forceinline__ void merge_16k(float v[VPT], float* s, int tid) {
  stage_exch<T512>(v, s, tid, 256, true);
  stage_exch<T512>(v, s, tid, 128, true);
  stage_exch<T512>(v, s, tid, 64, true);
  wave_ladder_tail_up<32>(v, tid, true);
}

// ---- final 32K bitonic merge (a=15, all ascending), 1024 threads (legacy) ----
__device__ __forceinline__ void merge_32k_final(float v[VPT], float* s, int tid) {
  stage_exch<T1024>(v, s, tid, 512, true);
  stage_exch<T1024>(v, s, tid, 256, true);
  stage_exch<T1024>(v, s, tid, 128, true);
  stage_exch<T1024>(v, s, tid, 64, true);
  wave_ladder_tail_up<32>(v, tid, true);
}

// ---- full 32K distributed bitonic sort, 1024 threads (legacy path) ----
__device__ __forceinline__ void sort_dist(float v[VPT], float* s, int tid) {
  low_merges_inreg(v);
  tail_inreg(v, (tid & 1) == 0);          // a=5
  wave_stages_and_tail<6, 1>(v, tid);
  wave_stages_and_tail<7, 2>(v, tid);
  wave_stages_and_tail<8, 4>(v, tid);
  wave_stages_and_tail<9, 8>(v, tid);
  wave_stages_and_tail<10, 16>(v, tid);
  wave_stages_and_tail<11, 32>(v, tid);
  stage_exch<T1024>(v, s, tid, 64, (tid & 128) == 0);
  wave_stages_and_tail<12, 32>(v, tid);
  {
    const bool u = (tid & 256) == 0;
    stage_exch<T1024>(v, s, tid, 128, u);
    stage_exch<T1024>(v, s, tid, 64, u);
  }
  wave_stages_and_tail<13, 32>(v, tid);
  {
    const bool u = (tid & 512) == 0;
    stage_exch<T1024>(v, s, tid, 256, u);
    stage_exch<T1024>(v, s, tid, 128, u);
    stage_exch<T1024>(v, s, tid, 64, u);
  }
  wave_stages_and_tail<14, 32>(v, tid);
  merge_32k_final(v, s, tid);
}

__device__ __forceinline__ void project_slice(const float4* base, float t0, float t1,
                                              int tid, float v[VPT]) {
#pragma unroll
  for (int q = 0; q < VPT / 2; q++) {
    float4 u = base[tid * (VPT / 2) + q];
    v[2 * q]     = fmaf(u.x, t0, u.y * t1);
    v[2 * q + 1] = fmaf(u.z, t0, u.w * t1);
  }
}

// b14 global stage: v[r] = h==0 ? min(lo[q], hi[q]) : max(lo[q], hi[q]),
// q = tid*32 + r, lo = g, hi = g + 16384.
__device__ __forceinline__ void b14_load(const float* g, int tid, int h,
                                         float v[VPT]) {
  const float4* lo = (const float4*)(g + (size_t)tid * VPT);
  const float4* hi = (const float4*)(g + 16384 + (size_t)tid * VPT);
#pragma unroll
  for (int q = 0; q < VPT / 4; q++) {
    float4 a = lo[q];
    float4 b = hi[q];
    if (h == 0) {
      v[4 * q]     = fminf(a.x, b.x);
      v[4 * q + 1] = fminf(a.y, b.y);
      v[4 * q + 2] = fminf(a.z, b.z);
      v[4 * q + 3] = fminf(a.w, b.w);
    } else {
      v[4 * q]     = fmaxf(a.x, b.x);
      v[4 * q + 1] = fmaxf(a.y, b.y);
      v[4 * q + 2] = fmaxf(a.z, b.z);
      v[4 * q + 3] = fmaxf(a.w, b.w);
    }
  }
}

// ==================== pipeline kernels ====================

// item = (slice_local<<2) | (arr<<1) | half;  arr: 0=X 1=Y
extern "C" __global__ void __launch_bounds__(T512, 8)
swd_halfsort(const float* __restrict__ x, const float* __restrict__ y,
             const float* __restrict__ proj, float* __restrict__ hs,
             int slice_base) {
  extern __shared__ float s[];
  const int item = blockIdx.x;
  const int sl   = item >> 2;
  const int arr  = (item >> 1) & 1;
  const int h    = item & 1;
  const int slice = slice_base + sl;
  const int p  = slice % Pp;
  const int bc = slice / Pp;
  const int tid = threadIdx.x;
  const float t0 = proj[2 * p];
  const float t1 = proj[2 * p + 1];
  const float* src = arr ? y : x;
  // half h covers points [h*16384, (h+1)*16384): offset h*Nn floats (D=2)
  const float4* base = (const float4*)(src + (size_t)bc * Nn * 2 + (size_t)h * Nn);
  float v[VPT];
  project_slice(base, t0, t1, tid, v);
  sort_16k(v, s, tid, h == 0);            // half 0 asc, half 1 desc -> bitonic
  float4* o = (float4*)(hs + ((size_t)sl * 2 + arr) * Nn + (size_t)h * (Nn / 2)
                        + (size_t)tid * VPT);
#pragma unroll
  for (int q = 0; q < VPT / 4; q++)
    o[q] = make_float4(v[4 * q], v[4 * q + 1], v[4 * q + 2], v[4 * q + 3]);
}

// Per-(slice,half) fused final merge + diff: b14 across halves via global
// reads, then independent 16K bitonic merge per array, diff in-register,
// one raw partial per (slice,half). 32KB LDS, 2 blocks/CU.
extern "C" __global__ void __launch_bounds__(T512, 4)
swd_mergehalf(const float* __restrict__ hs, float* __restrict__ w2h,
              int slice_base) {
  extern __shared__ float s[];
  __shared__ float wsum[T512 / 64];
  const int sl  = blockIdx.x >> 1;
  const int h   = blockIdx.x & 1;
  const int slice = slice_base + sl;
  const int tid = threadIdx.x;
  const float* gx = hs + (size_t)sl * 2 * Nn;
  const float* gy = gx + Nn;
  float xv[VPT], yv[VPT];
  b14_load(gx, tid, h, xv);
  b14_load(gy, tid, h, yv);
  merge_16k(xv, s, tid);
  merge_16k(yv, s, tid);

  float acc = 0.f;
#pragma unroll
  for (int r = 0; r < VPT; r++) {
    float d = xv[r] - yv[r];
    acc = fmaf(d, d, acc);
  }
#pragma unroll
  for (int off = 32; off > 0; off >>= 1)
    acc += __shfl_down(acc, off, 64);
  if ((tid & 63) == 0) wsum[tid >> 6] = acc;
  __syncthreads();
  if (tid == 0) {
    float t = 0.f;
#pragma unroll
    for (int w = 0; w < T512 / 64; w++) t += wsum[w];
    w2h[(size_t)slice * 2 + h] = t;       // raw partial; scaled in swd_final
  }
}

// ==================== legacy kernels (fallback for tiny ws) ====================

extern "C" __global__ void __launch_bounds__(T1024, 8)
swd_sortx(const float* __restrict__ x, const float* __restrict__ proj,
          float* __restrict__ xs, int slice_base) {
  extern __shared__ float s[];
  const int slice = slice_base + blockIdx.x;
  const int p  = slice % Pp;
  const int bc = slice / Pp;
  const int tid = threadIdx.x;
  const float t0 = proj[2 * p];
  const float t1 = proj[2 * p + 1];
  float v[VPT];
  project_slice((const float4*)(x + (size_t)bc * Nn * 2), t0, t1, tid, v);
  sort_dist(v, s, tid);
  float4* o = (float4*)(xs + (size_t)blockIdx.x * Nn + tid * VPT);
#pragma unroll
  for (int q = 0; q < VPT / 4; q++)
    o[q] = make_float4(v[4 * q], v[4 * q + 1], v[4 * q + 2], v[4 * q + 3]);
}

extern "C" __global__ void __launch_bounds__(T1024, 8)
swd_sorty(const float* __restrict__ y, const float* __restrict__ proj,
          const float* __restrict__ xs, float* __restrict__ w2h, int slice_base) {
  extern __shared__ float s[];
  __shared__ float wsum[T1024 / 64];
  const int slice = slice_base + blockIdx.x;
  const int p  = slice % Pp;
  const int bc = slice / Pp;
  const int tid = threadIdx.x;
  const float t0 = proj[2 * p];
  const float t1 = proj[2 * p + 1];
  float v[VPT];
  project_slice((const float4*)(y + (size_t)bc * Nn * 2), t0, t1, tid, v);
  sort_dist(v, s, tid);

  const float4* xr = (const float4*)(xs + (size_t)blockIdx.x * Nn + tid * VPT);
  float acc = 0.f;
#pragma unroll
  for (int q = 0; q < VPT / 4; q++) {
    float4 u = xr[q];
    float d0 = u.x - v[4 * q];
    float d1 = u.y - v[4 * q + 1];
    float d2 = u.z - v[4 * q + 2];
    float d3 = u.w - v[4 * q + 3];
    acc = fmaf(d0, d0, acc);
    acc = fmaf(d1, d1, acc);
    acc = fmaf(d2, d2, acc);
    acc = fmaf(d3, d3, acc);
  }
#pragma unroll
  for (int off = 32; off > 0; off >>= 1)
    acc += __shfl_down(acc, off, 64);
  if ((tid & 63) == 0) wsum[tid >> 6] = acc;
  __syncthreads();
  if (tid == 0) {
    float t = 0.f;
#pragma unroll
    for (int w = 0; w < T1024 / 64; w++) t += wsum[w];
    w2h[(size_t)slice * 2] = t;
    w2h[(size_t)slice * 2 + 1] = 0.f;
  }
}

extern "C" __global__ void swd_final(const float* __restrict__ w2h,
                                     float* __restrict__ out) {
  __shared__ float sred[Bb * Cc];
  int t = threadIdx.x;
  if (t < Bb * Cc) {
    float sum = 0.f;
    for (int p = 0; p < Pp; p++) {
      int sl = t * Pp + p;
      sum += (w2h[sl * 2] + w2h[sl * 2 + 1]) * (1.0f / Nn);
    }
    sred[t] = sqrtf(sum * (1.0f / Pp));
  }
  __syncthreads();
  if (t == 0) {
    float a = 0.f;
    for (int i = 0; i < Bb * Cc; i++) a += sred[i];
    out[0] = a * (1.0f / (Bb * Cc));
  }
}

extern "C" void kernel_launch(void* const* d_in, const int* in_sizes, int n_in,
                              void* d_out, int out_size, void* d_ws, size_t ws_size,
                              hipStream_t stream) {
  const float* x    = (const float*)d_in[0];
  const float* y    = (const float*)d_in[1];
  const float* proj = (const float*)d_in[2];
  float* w2h = (float*)d_ws;                       // first 16KB: per-half partials
  float* hs  = (float*)((char*)d_ws + W2_BYTES);   // staging (sorted halves)
  float* out = (float*)d_out;

  const size_t lds_full = (size_t)LDS_FLOATS_FULL * sizeof(float);  // 64 KB
  const size_t lds_half = (size_t)LDS_FLOATS_HALF * sizeof(float);  // 32 KB
  (void)hipFuncSetAttribute((const void*)swd_halfsort,
                            hipFuncAttributeMaxDynamicSharedMemorySize, (int)lds_half);
  (void)hipFuncSetAttribute((const void*)swd_mergehalf,
                            hipFuncAttributeMaxDynamicSharedMemorySize, (int)lds_half);
  (void)hipFuncSetAttribute((const void*)swd_sortx,
                            hipFuncAttributeMaxDynamicSharedMemorySize, (int)lds_full);
  (void)hipFuncSetAttribute((const void*)swd_sorty,
                            hipFuncAttributeMaxDynamicSharedMemorySize, (int)lds_full);

  const size_t avail = ws_size > W2_BYTES ? ws_size - W2_BYTES : 0;
  const size_t per_slice_pipe = (size_t)2 * Nn * sizeof(float);   // 256 KB (X+Y)
  int ch_max = (int)(avail / per_slice_pipe);
  if (ch_max > SLICES) ch_max = SLICES;

  if (ch_max >= 1) {
    // equalized chunks: minimizes total round-count AND avoids a tiny
    // remainder chunk paying a full block-latency round.
    const int nch = (SLICES + ch_max - 1) / ch_max;
    const int ch  = (SLICES + nch - 1) / nch;
    for (int base = 0; base < SLICES; base += ch) {
      int n = SLICES - base < ch ? SLICES - base : ch;
      hipLaunchKernelGGL(swd_halfsort, dim3(n * 4), dim3(T512), lds_half,
                         stream, x, y, proj, hs, base);
      hipLaunchKernelGGL(swd_mergehalf, dim3(n * 2), dim3(T512), lds_half,
                         stream, hs, w2h, base);
    }
  } else {
    // ---- legacy path (chunked monolithic sorts) ----
    float* xs = hs;
    const size_t slice_bytes = (size_t)Nn * sizeof(float);
    int chunk = (int)(avail / slice_bytes);
    if (chunk > SLICES) chunk = SLICES;
    if (chunk < 1) chunk = 1;
    for (int base = 0; base < SLICES; base += chunk) {
      int n = SLICES - base < chunk ? SLICES - base : chunk;
      hipLaunchKernelGGL(swd_sortx, dim3(n), dim3(T1024), lds_full, stream,
                         x, proj, xs, base);
      hipLaunchKernelGGL(swd_sorty, dim3(n), dim3(T1024), lds_full, stream,
                         y, proj, xs, w2h, base);
    }
  }
  hipLaunchKernelGGL(swd_final, dim3(1), dim3(64), 0, stream, w2h, out);
}

// Round 6
// 832.186 us; speedup vs baseline: 1.5481x; 1.5481x over previous
//
#include <hip/hip_runtime.h>
#include <math.h>

// Sliced Wasserstein-2: for each (b,c,p): W2^2 = mean_i (sort(X@theta_p) - sort(Y@theta_p))^2
// loss = mean_{b,c} sqrt(mean_p W2^2)
//
// R22 = R17 monolithic structure (proven 871us; half-split pipelines R19-R21
// all lost their packing gain to the merge phase's memory traffic) + ONE
// structural fix: sortx and sorty fused into a single 3200-block dispatch
// with an atomic ticket queue. 3200 units over 512 slots ~= 7 round-times
// vs R17's 4+4 = 8 (two ceil-quantized dispatches) -> ~-110us.
//   ticket 0..1599    : sort X slice, stage to xs, release flag bit
//   ticket 1600..3199 : sort Y slice, THEN acquire flag (spin never engages:
//                       partner popped >=1600 tickets earlier by a block that
//                       is resident-or-finished), diff vs xs, reduce to w2.
// Flags = 1600 bits in 50 words + ticket word, packed in the spare bytes of
// the 8KB w2 region -> workspace need identical to R17 (known to fit).
// swd_reset re-zeros flags+ticket every launch (graph-replay safe).
// Sort network byte-identical to R17 -> absmax 0.

namespace {
constexpr int Bb = 8, Cc = 4, Nn = 32768, Pp = 50;
constexpr int T1024 = 1024;
constexpr int VPT = 32;                    // values per thread
constexpr int SLICES = Bb * Cc * Pp;       // 1600
constexpr int FLAG_WORDS = (SLICES + 31) / 32;  // 50
constexpr size_t W2_BYTES = 8192;          // w2[1600] + flags + ticket
constexpr size_t FLAGS_OFF = 6400;         // after w2 floats
constexpr size_t TICKET_OFF = 6656;
constexpr int LDS_FLOATS_FULL = Nn / 2;    // 16384 floats = 64 KB
}

__device__ __forceinline__ void ce(float& a, float& b, bool up) {
  float lo = fminf(a, b);
  float hi = fmaxf(a, b);
  a = up ? lo : hi;
  b = up ? hi : lo;
}

// 2-VALU compare-select CE: keepMin ? min(v,o) : max(v,o); ties resolve
// consistently on both partners (multiset preserved).
__device__ __forceinline__ float sel_ce(float v, float o, bool keepMin) {
  return ((o < v) != keepMin) ? v : o;
}

// DPP lane move with compile-time control word.
// 0xB1 = quad_perm(1,0,3,2) = xor1; 0x4E = quad_perm(2,3,0,1) = xor2;
// 0x128 = row_ror:8 = xor8 on each 16-lane row.
template<int CTRL>
__device__ __forceinline__ float dpp_move(float x) {
  int i = __builtin_amdgcn_update_dpp(0, __float_as_int(x), CTRL, 0xF, 0xF, true);
  return __int_as_float(i);
}

// cross-lane CE stage with xor-mask M (M=1,2,8 via DPP; M=4,16,32 via bpermute)
template<int M>
__device__ __forceinline__ void stage_xlane(float v[VPT], int tid, bool up) {
  const bool keepMin = (up == ((tid & M) == 0));
  if constexpr (M == 1 || M == 2 || M == 8) {
    constexpr int ctrl = (M == 1) ? 0xB1 : (M == 2) ? 0x4E : 0x128;
#pragma unroll
    for (int r = 0; r < VPT; r++) {
      float o = dpp_move<ctrl>(v[r]);
      v[r] = sel_ce(v[r], o, keepMin);
    }
  } else {
    const int addr = (((tid & 63) ^ M) << 2);
#pragma unroll
    for (int r = 0; r < VPT; r++) {
      float o = __int_as_float(
          __builtin_amdgcn_ds_bpermute(addr, __float_as_int(v[r])));
      v[r] = sel_ce(v[r], o, keepMin);
    }
  }
}

// 5-stage in-register network on the reg-index bits (j=16..1), direction
// uniform per thread via sign-flip trick.
__device__ __forceinline__ void tail_inreg(float v[VPT], bool up) {
  const unsigned flip = up ? 0u : 0x80000000u;
#pragma unroll
  for (int r = 0; r < VPT; r++)
    v[r] = __int_as_float(__float_as_int(v[r]) ^ flip);
#pragma unroll
  for (int j = 16; j > 0; j >>= 1) {
#pragma unroll
    for (int r = 0; r < VPT; r++) {
      if (!(r & j)) {
        float a = v[r], b = v[r | j];
        v[r] = fminf(a, b);
        v[r | j] = fmaxf(a, b);
      }
    }
  }
#pragma unroll
  for (int r = 0; r < VPT; r++)
    v[r] = __int_as_float(__float_as_int(v[r]) ^ flip);
}

// wave-local cross stages (m = MTOP..1) + tail, explicit direction
template<int MTOP>
__device__ __forceinline__ void wave_ladder_tail_up(float v[VPT], int tid, bool up) {
  if constexpr (MTOP >= 32) stage_xlane<32>(v, tid, up);
  if constexpr (MTOP >= 16) stage_xlane<16>(v, tid, up);
  if constexpr (MTOP >= 8)  stage_xlane<8>(v, tid, up);
  if constexpr (MTOP >= 4)  stage_xlane<4>(v, tid, up);
  if constexpr (MTOP >= 2)  stage_xlane<2>(v, tid, up);
  if constexpr (MTOP >= 1)  stage_xlane<1>(v, tid, up);
  tail_inreg(v, up);
}

// direction from bit A of global rank (= tid bit A-5)
template<int A, int MTOP>
__device__ __forceinline__ void wave_stages_and_tail(float v[VPT], int tid) {
  wave_ladder_tail_up<MTOP>(v, tid, ((tid & (1 << (A - 5))) == 0));
}

// Wave-crossing exchange stage (xor-mask m>=64 on tid), element-wise,
// SPLIT through a half-size buffer in two 16-reg rounds. Column layout
// s[r*NT+tid]: conflict-free. Safe split: round-2 writes happen after the
// barrier that ends round-1 reads; v[] is preserved across reads.
template<int NT>
__device__ __forceinline__ void stage_exch(float v[VPT], float* s, int tid,
                                           int m, bool up) {
  const bool keepMin = (up == ((tid & m) == 0));
  const int pt = tid ^ m;
#pragma unroll
  for (int h = 0; h < 2; h++) {
    __syncthreads();                  // prior users of s must finish
#pragma unroll
    for (int r = 0; r < VPT / 2; r++)
      s[r * NT + tid] = v[h * (VPT / 2) + r];
    __syncthreads();
#pragma unroll
    for (int r = 0; r < VPT / 2; r++) {
      float o = s[r * NT + pt];
      v[h * (VPT / 2) + r] = sel_ce(v[h * (VPT / 2) + r], o, keepMin);
    }
  }
}

// in-register merges a=1..4 (k=2..16), compile-time directions
__device__ __forceinline__ void low_merges_inreg(float v[VPT]) {
#pragma unroll
  for (int k = 2; k <= 16; k <<= 1) {
#pragma unroll
    for (int j = k >> 1; j > 0; j >>= 1) {
#pragma unroll
      for (int r = 0; r < VPT; r++)
        if (!(r & j)) ce(v[r], v[r | j], (r & k) == 0);
    }
  }
}

// ---- full 32K distributed bitonic sort, 1024 threads (proven R17 network) ----
__device__ __forceinline__ void sort_dist(float v[VPT], float* s, int tid) {
  low_merges_inreg(v);
  tail_inreg(v, (tid & 1) == 0);          // a=5
  wave_stages_and_tail<6, 1>(v, tid);
  wave_stages_and_tail<7, 2>(v, tid);
  wave_stages_and_tail<8, 4>(v, tid);
  wave_stages_and_tail<9, 8>(v, tid);
  wave_stages_and_tail<10, 16>(v, tid);
  wave_stages_and_tail<11, 32>(v, tid);
  stage_exch<T1024>(v, s, tid, 64, (tid & 128) == 0);
  wave_stages_and_tail<12, 32>(v, tid);
  {
    const bool u = (tid & 256) == 0;
    stage_exch<T1024>(v, s, tid, 128, u);
    stage_exch<T1024>(v, s, tid, 64, u);
  }
  wave_stages_and_tail<13, 32>(v, tid);
  {
    const bool u = (tid & 512) == 0;
    stage_exch<T1024>(v, s, tid, 256, u);
    stage_exch<T1024>(v, s, tid, 128, u);
    stage_exch<T1024>(v, s, tid, 64, u);
  }
  wave_stages_and_tail<14, 32>(v, tid);
  stage_exch<T1024>(v, s, tid, 512, true);
  stage_exch<T1024>(v, s, tid, 256, true);
  stage_exch<T1024>(v, s, tid, 128, true);
  stage_exch<T1024>(v, s, tid, 64, true);
  wave_ladder_tail_up<32>(v, tid, true);
}

__device__ __forceinline__ void project_slice(const float4* base, float t0, float t1,
                                              int tid, float v[VPT]) {
#pragma unroll
  for (int q = 0; q < VPT / 2; q++) {
    float4 u = base[tid * (VPT / 2) + q];
    v[2 * q]     = fmaf(u.x, t0, u.y * t1);
    v[2 * q + 1] = fmaf(u.z, t0, u.w * t1);
  }
}

// ==================== fused single-dispatch kernel ====================

extern "C" __global__ void __launch_bounds__(T1024, 8)
swd_fused(const float* __restrict__ x, const float* __restrict__ y,
          const float* __restrict__ proj, float* __restrict__ w2,
          unsigned* __restrict__ flags, unsigned* __restrict__ ticket,
          float* __restrict__ xs) {
  extern __shared__ float s[];
  __shared__ unsigned su;
  __shared__ float wsum[T1024 / 64];
  const int tid = threadIdx.x;
  if (tid == 0) su = atomicAdd(ticket, 1u);
  __syncthreads();
  const unsigned unit = su;

  if (unit < (unsigned)SLICES) {
    // ---- sort X slice, stage, release flag ----
    const int slice = (int)unit;
    const int p  = slice % Pp;
    const int bc = slice / Pp;
    const float t0 = proj[2 * p];
    const float t1 = proj[2 * p + 1];
    float v[VPT];
    project_slice((const float4*)(x + (size_t)bc * Nn * 2), t0, t1, tid, v);
    sort_dist(v, s, tid);
    float4* o = (float4*)(xs + (size_t)slice * Nn + tid * VPT);
#pragma unroll
    for (int q = 0; q < VPT / 4; q++)
      o[q] = make_float4(v[4 * q], v[4 * q + 1], v[4 * q + 2], v[4 * q + 3]);
    __syncthreads();                        // all stores issued & drained
    if (tid == 0) {
      __threadfence();                      // device-scope release
      atomicOr(&flags[slice >> 5], 1u << (slice & 31));
    }
  } else {
    // ---- sort Y slice, acquire X, diff, reduce ----
    const int slice = (int)unit - SLICES;
    const int p  = slice % Pp;
    const int bc = slice / Pp;
    const float t0 = proj[2 * p];
    const float t1 = proj[2 * p + 1];
    float v[VPT];
    project_slice((const float4*)(y + (size_t)bc * Nn * 2), t0, t1, tid, v);
    sort_dist(v, s, tid);

    // acquire: partner's ticket was >=1600 pops earlier -> resident or done;
    // our own ~400us sort already covered it, spin is a safety net only.
    if (tid == 0) {
      while (((atomicAdd(&flags[slice >> 5], 0u) >> (slice & 31)) & 1u) == 0u) {}
      __threadfence();                      // device-scope acquire
    }
    __syncthreads();

    const float4* xr = (const float4*)(xs + (size_t)slice * Nn + tid * VPT);
    float acc = 0.f;
#pragma unroll
    for (int q = 0; q < VPT / 4; q++) {
      float4 u = xr[q];
      float d0 = u.x - v[4 * q];
      float d1 = u.y - v[4 * q + 1];
      float d2 = u.z - v[4 * q + 2];
      float d3 = u.w - v[4 * q + 3];
      acc = fmaf(d0, d0, acc);
      acc = fmaf(d1, d1, acc);
      acc = fmaf(d2, d2, acc);
      acc = fmaf(d3, d3, acc);
    }
#pragma unroll
    for (int off = 32; off > 0; off >>= 1)
      acc += __shfl_down(acc, off, 64);
    if ((tid & 63) == 0) wsum[tid >> 6] = acc;
    __syncthreads();
    if (tid == 0) {
      float t = 0.f;
#pragma unroll
      for (int w = 0; w < T1024 / 64; w++) t += wsum[w];
      w2[slice] = t * (1.0f / Nn);
    }
  }
}

extern "C" __global__ void swd_reset(unsigned* __restrict__ flags,
                                     unsigned* __restrict__ ticket) {
  int t = threadIdx.x;
  if (t < FLAG_WORDS) flags[t] = 0u;
  if (t == 63) *ticket = 0u;
}

// ==================== legacy kernels (fallback for tiny ws) ====================

extern "C" __global__ void __launch_bounds__(T1024, 8)
swd_sortx(const float* __restrict__ x, const float* __restrict__ proj,
          float* __restrict__ xs, int slice_base) {
  extern __shared__ float s[];
  const int slice = slice_base + blockIdx.x;
  const int p  = slice % Pp;
  const int bc = slice / Pp;
  const int tid = threadIdx.x;
  const float t0 = proj[2 * p];
  const float t1 = proj[2 * p + 1];
  float v[VPT];
  project_slice((const float4*)(x + (size_t)bc * Nn * 2), t0, t1, tid, v);
  sort_dist(v, s, tid);
  float4* o = (float4*)(xs + (size_t)blockIdx.x * Nn + tid * VPT);
#pragma unroll
  for (int q = 0; q < VPT / 4; q++)
    o[q] = make_float4(v[4 * q], v[4 * q + 1], v[4 * q + 2], v[4 * q + 3]);
}

extern "C" __global__ void __launch_bounds__(T1024, 8)
swd_sorty(const float* __restrict__ y, const float* __restrict__ proj,
          const float* __restrict__ xs, float* __restrict__ w2, int slice_base) {
  extern __shared__ float s[];
  __shared__ float wsum[T1024 / 64];
  const int slice = slice_base + blockIdx.x;
  const int p  = slice % Pp;
  const int bc = slice / Pp;
  const int tid = threadIdx.x;
  const float t0 = proj[2 * p];
  const float t1 = proj[2 * p + 1];
  float v[VPT];
  project_slice((const float4*)(y + (size_t)bc * Nn * 2), t0, t1, tid, v);
  sort_dist(v, s, tid);

  const float4* xr = (const float4*)(xs + (size_t)blockIdx.x * Nn + tid * VPT);
  float acc = 0.f;
#pragma unroll
  for (int q = 0; q < VPT / 4; q++) {
    float4 u = xr[q];
    float d0 = u.x - v[4 * q];
    float d1 = u.y - v[4 * q + 1];
    float d2 = u.z - v[4 * q + 2];
    float d3 = u.w - v[4 * q + 3];
    acc = fmaf(d0, d0, acc);
    acc = fmaf(d1, d1, acc);
    acc = fmaf(d2, d2, acc);
    acc = fmaf(d3, d3, acc);
  }
#pragma unroll
  for (int off = 32; off > 0; off >>= 1)
    acc += __shfl_down(acc, off, 64);
  if ((tid & 63) == 0) wsum[tid >> 6] = acc;
  __syncthreads();
  if (tid == 0) {
    float t = 0.f;
#pragma unroll
    for (int w = 0; w < T1024 / 64; w++) t += wsum[w];
    w2[slice] = t * (1.0f / Nn);
  }
}

extern "C" __global__ void swd_final(const float* __restrict__ w2,
                                     float* __restrict__ out) {
  __shared__ float sred[Bb * Cc];
  int t = threadIdx.x;
  if (t < Bb * Cc) {
    float sum = 0.f;
    for (int p = 0; p < Pp; p++) sum += w2[t * Pp + p];
    sred[t] = sqrtf(sum * (1.0f / Pp));
  }
  __syncthreads();
  if (t == 0) {
    float a = 0.f;
    for (int i = 0; i < Bb * Cc; i++) a += sred[i];
    out[0] = a * (1.0f / (Bb * Cc));
  }
}

extern "C" void kernel_launch(void* const* d_in, const int* in_sizes, int n_in,
                              void* d_out, int out_size, void* d_ws, size_t ws_size,
                              hipStream_t stream) {
  const float* x    = (const float*)d_in[0];
  const float* y    = (const float*)d_in[1];
  const float* proj = (const float*)d_in[2];
  float* w2       = (float*)d_ws;                  // 6400 B
  unsigned* flags = (unsigned*)((char*)d_ws + FLAGS_OFF);   // 200 B
  unsigned* tick  = (unsigned*)((char*)d_ws + TICKET_OFF);  // 4 B
  float* xs       = (float*)((char*)d_ws + W2_BYTES);       // sorted-X staging
  float* out      = (float*)d_out;

  const size_t lds_full = (size_t)LDS_FLOATS_FULL * sizeof(float);  // 64 KB
  (void)hipFuncSetAttribute((const void*)swd_fused,
                            hipFuncAttributeMaxDynamicSharedMemorySize, (int)lds_full);
  (void)hipFuncSetAttribute((const void*)swd_sortx,
                            hipFuncAttributeMaxDynamicSharedMemorySize, (int)lds_full);
  (void)hipFuncSetAttribute((const void*)swd_sorty,
                            hipFuncAttributeMaxDynamicSharedMemorySize, (int)lds_full);

  const size_t avail = ws_size > W2_BYTES ? ws_size - W2_BYTES : 0;
  const size_t slice_bytes = (size_t)Nn * sizeof(float);            // 128 KB

  if (avail >= (size_t)SLICES * slice_bytes) {
    // ---- single fused dispatch: 3200 ticket-ordered units ----
    hipLaunchKernelGGL(swd_reset, dim3(1), dim3(64), 0, stream, flags, tick);
    hipLaunchKernelGGL(swd_fused, dim3(SLICES * 2), dim3(T1024), lds_full,
                       stream, x, y, proj, w2, flags, tick, xs);
  } else {
    // ---- legacy chunked two-kernel path ----
    int chunk = (int)(avail / slice_bytes);
    if (chunk > SLICES) chunk = SLICES;
    if (chunk < 1) chunk = 1;
    for (int base = 0; base < SLICES; base += chunk) {
      int n = SLICES - base < chunk ? SLICES - base : chunk;
      hipLaunchKernelGGL(swd_sortx, dim3(n), dim3(T1024), lds_full, stream,
                         x, proj, xs, base);
      hipLaunchKernelGGL(swd_sorty, dim3(n), dim3(T1024), lds_full, stream,
                         y, proj, xs, w2, base);
    }
  }
  hipLaunchKernelGGL(swd_final, dim3(1), dim3(64), 0, stream, w2, out);
}